// Round 2
// baseline (399.472 us; speedup 1.0000x reference)
//
#include <hip/hip_runtime.h>
#include <math.h>

#define EMB   4096
#define DIM   4096
#define TPREV 8192
#define TTOT  8193   // TPREV + 1 (appended current step)

// ws layout (floats):
//   [0,4096)        q
//   [4096,8192)     k
//   [8192,12288)    v
//   [12288,20481)   scores / a   (8193)
//   [20544, 20544+128*8192)  score partials: partial[chunk][t], 4 MB
#define WS_Q        0
#define WS_K        DIM
#define WS_V        (2*DIM)
#define WS_A        (3*DIM)
#define WS_PART     20544
#define NCHUNK      128
#define CHUNK_ROWS  32   // 4096 / 128

// ---------------------------------------------------------------------------
// K1: q,k,v GEMVs (wave-per-row, float4 coalesced).
// grid 3072 x 256 = 12288 waves -> 3 matrices x 4096 rows. 12 blocks/CU.
__global__ __launch_bounds__(256) void qkv_kernel(
    const float* __restrict__ x,
    const float* __restrict__ Wq, const float* __restrict__ Wk,
    const float* __restrict__ Wv, float* __restrict__ ws) {
    int wave = threadIdx.x >> 6;
    int lane = threadIdx.x & 63;
    int g = blockIdx.x * 4 + wave;      // global wave id, 0..12287
    int m = g >> 12;                    // which matrix (0..2)
    int r = g & 4095;                   // row
    const float* W = (m == 0) ? Wq : (m == 1) ? Wk : Wv;

    const float4* row = (const float4*)(W + (size_t)r * EMB);
    const float4* xv  = (const float4*)x;

    float acc = 0.0f;
#pragma unroll 8
    for (int i = 0; i < EMB / 256; ++i) {       // 16 iterations
        float4 a = row[i * 64 + lane];
        float4 b = xv[i * 64 + lane];
        acc += a.x * b.x + a.y * b.y + a.z * b.z + a.w * b.w;
    }
#pragma unroll
    for (int off = 32; off > 0; off >>= 1) acc += __shfl_down(acc, off, 64);
    if (lane == 0) ws[m * DIM + r] = acc;
}

// ---------------------------------------------------------------------------
// K2: score partials, NO atomics. grid (8, 128) = 1024 blocks = 4/CU.
//   blockIdx.x = t-tile (1024 wide), blockIdx.y = d-chunk (32 rows).
// Each thread owns 4 consecutive t (float4 coalesced), accumulates over the
// 32 rows of its chunk, writes one float4 partial.
__global__ __launch_bounds__(256) void score_kernel(
    const float* __restrict__ Kc, float* __restrict__ ws) {
    const float* q = ws + WS_Q;
    float* part    = ws + WS_PART;

    __shared__ float qs[CHUNK_ROWS];
    int d0 = blockIdx.y * CHUNK_ROWS;
    if (threadIdx.x < CHUNK_ROWS) qs[threadIdx.x] = q[d0 + threadIdx.x];
    __syncthreads();

    int t = blockIdx.x * 1024 + threadIdx.x * 4;
    float4 acc = {0.f, 0.f, 0.f, 0.f};
#pragma unroll 8
    for (int i = 0; i < CHUNK_ROWS; ++i) {
        const float4 kv = *(const float4*)(Kc + (size_t)(d0 + i) * TPREV + t);
        float qd = qs[i];
        acc.x += qd * kv.x;
        acc.y += qd * kv.y;
        acc.z += qd * kv.z;
        acc.w += qd * kv.w;
    }
    *(float4*)(part + (size_t)blockIdx.y * TPREV + t) = acc;
}

// ---------------------------------------------------------------------------
// K3: reduce partials across 128 chunks + sigmoid. grid 33 x 256.
// Blocks 0..31: a[t] = sigmoid(sum_c part[c][t] / 64).
// Block 32: tail a[8192] = sigmoid(dot(q,k)/64) via LDS tree reduce.
__global__ __launch_bounds__(256) void reduce_sigmoid_kernel(
    float* __restrict__ ws) {
    float* scores      = ws + WS_A;
    const float* part  = ws + WS_PART;

    if (blockIdx.x < 32) {
        int t = blockIdx.x * 256 + threadIdx.x;
        float s = 0.0f;
#pragma unroll 16
        for (int c = 0; c < NCHUNK; ++c) s += part[(size_t)c * TPREV + t];
        s *= 0.015625f;   // 1/sqrt(4096)
        scores[t] = 1.0f / (1.0f + __expf(-s));
    } else {
        // tail: dot(q, k) over 4096 elems, 16 per thread
        const float* q = ws + WS_Q;
        const float* k = ws + WS_K;
        float s = 0.0f;
        int base = threadIdx.x * 16;
#pragma unroll 16
        for (int i = 0; i < 16; ++i) s += q[base + i] * k[base + i];
        __shared__ float red[256];
        red[threadIdx.x] = s;
        __syncthreads();
        for (int off = 128; off > 0; off >>= 1) {
            if (threadIdx.x < off) red[threadIdx.x] += red[threadIdx.x + off];
            __syncthreads();
        }
        if (threadIdx.x == 0) {
            float v = red[0] * 0.015625f;
            scores[TPREV] = 1.0f / (1.0f + __expf(-v));
        }
    }
}

// ---------------------------------------------------------------------------
// K4: z[d] = dot(V_cache[d,:], a[0:8192]) + v[d] * a[8192]
// wave-per-row; 1024 blocks = 4/CU; a (32KB) L2-resident broadcast.
__global__ __launch_bounds__(256) void out_kernel(
    const float* __restrict__ Vc, const float* __restrict__ ws,
    float* __restrict__ out) {
    const float* vvec = ws + WS_V;
    const float* a    = ws + WS_A;

    int wave = threadIdx.x >> 6;
    int lane = threadIdx.x & 63;
    int d = blockIdx.x * 4 + wave;

    const float4* row = (const float4*)(Vc + (size_t)d * TPREV);
    const float4* av  = (const float4*)a;

    float acc = 0.0f;
#pragma unroll 8
    for (int i = 0; i < TPREV / 256; ++i) {     // 32 iterations
        float4 vv = row[i * 64 + lane];
        float4 aa = av[i * 64 + lane];
        acc += vv.x * aa.x + vv.y * aa.y + vv.z * aa.z + vv.w * aa.w;
    }
#pragma unroll
    for (int off = 32; off > 0; off >>= 1) acc += __shfl_down(acc, off, 64);
    if (lane == 0) out[d] = acc + vvec[d] * a[TPREV];
}

// ---------------------------------------------------------------------------
extern "C" void kernel_launch(void* const* d_in, const int* in_sizes, int n_in,
                              void* d_out, int out_size, void* d_ws, size_t ws_size,
                              hipStream_t stream) {
    const float* x  = (const float*)d_in[0];
    const float* Wq = (const float*)d_in[1];
    const float* Wk = (const float*)d_in[2];
    const float* Wv = (const float*)d_in[3];
    const float* Kc = (const float*)d_in[4];
    const float* Vc = (const float*)d_in[5];
    float* out = (float*)d_out;
    float* ws  = (float*)d_ws;

    qkv_kernel<<<3072, 256, 0, stream>>>(x, Wq, Wk, Wv, ws);
    score_kernel<<<dim3(8, 128), 256, 0, stream>>>(Kc, ws);
    reduce_sigmoid_kernel<<<33, 256, 0, stream>>>(ws);
    out_kernel<<<1024, 256, 0, stream>>>(Vc, ws, out);
}

// Round 3
// 389.946 us; speedup vs baseline: 1.0244x; 1.0244x over previous
//
#include <hip/hip_runtime.h>
#include <math.h>

#define EMB   4096
#define DIM   4096
#define TPREV 8192
#define TTOT  8193   // TPREV + 1

// ws layout (floats):
//   [0,4096)        q
//   [4096,8192)     k
//   [8192,12288)    v
//   [12288,20481)   scores / a   (8193)
//   [20544, ...)    score partials: part[chunk][t], 128 x 8192 floats (4 MB)
#define WS_Q        0
#define WS_K        DIM
#define WS_V        (2*DIM)
#define WS_A        (3*DIM)
#define WS_PART     20544
#define NCHUNK      128
#define CHUNK_ROWS  32   // 4096 / 128

__device__ __forceinline__ float dot4(float4 a, float4 b) {
    return a.x * b.x + a.y * b.y + a.z * b.z + a.w * b.w;
}

// ---------------------------------------------------------------------------
// K1: q,k,v GEMVs. Block-per-row: 12288 blocks x 256 threads.
// Each thread issues 4 independent W float4 loads + 4 x float4 loads (L1-hot)
// BEFORE any use -> 4+ loads in flight per thread, latency hidden.
__global__ __launch_bounds__(256) void qkv_kernel(
    const float* __restrict__ x,
    const float* __restrict__ Wq, const float* __restrict__ Wk,
    const float* __restrict__ Wv, float* __restrict__ ws) {
    int b = blockIdx.x;                 // 0..12287
    int m = b >> 12;                    // matrix 0..2
    int r = b & 4095;                   // row
    const float* W = (m == 0) ? Wq : (m == 1) ? Wk : Wv;
    const float4* row = (const float4*)(W + (size_t)r * EMB);
    const float4* xv  = (const float4*)x;
    int tid = threadIdx.x;

    // 8 independent loads, no use until all issued
    float4 w0 = row[tid];
    float4 w1 = row[tid + 256];
    float4 w2 = row[tid + 512];
    float4 w3 = row[tid + 768];
    float4 x0 = xv[tid];
    float4 x1 = xv[tid + 256];
    float4 x2 = xv[tid + 512];
    float4 x3 = xv[tid + 768];

    float s = dot4(w0, x0) + dot4(w1, x1) + dot4(w2, x2) + dot4(w3, x3);

#pragma unroll
    for (int off = 32; off > 0; off >>= 1) s += __shfl_down(s, off, 64);

    __shared__ float red[4];
    if ((tid & 63) == 0) red[tid >> 6] = s;
    __syncthreads();
    if (tid == 0) ws[m * DIM + r] = red[0] + red[1] + red[2] + red[3];
}

// ---------------------------------------------------------------------------
// K2: score partials. grid (8, 128) = 1024 blocks.
// blockIdx.x = t-tile (1024 wide), blockIdx.y = d-chunk (32 rows).
// Inner loop: groups of 4 INDEPENDENT row loads issued before the FMAs.
__global__ __launch_bounds__(256) void score_kernel(
    const float* __restrict__ Kc, float* __restrict__ ws) {
    const float* q = ws + WS_Q;
    float* part    = ws + WS_PART;

    __shared__ float qs[CHUNK_ROWS];
    int d0 = blockIdx.y * CHUNK_ROWS;
    if (threadIdx.x < CHUNK_ROWS) qs[threadIdx.x] = q[d0 + threadIdx.x];
    __syncthreads();

    size_t t = (size_t)blockIdx.x * 1024 + threadIdx.x * 4;
    const float* base = Kc + (size_t)d0 * TPREV + t;

    float4 acc = {0.f, 0.f, 0.f, 0.f};
#pragma unroll
    for (int g = 0; g < CHUNK_ROWS / 4; ++g) {   // 8 groups
        float4 k0 = *(const float4*)(base + (size_t)(4 * g + 0) * TPREV);
        float4 k1 = *(const float4*)(base + (size_t)(4 * g + 1) * TPREV);
        float4 k2 = *(const float4*)(base + (size_t)(4 * g + 2) * TPREV);
        float4 k3 = *(const float4*)(base + (size_t)(4 * g + 3) * TPREV);
        float q0 = qs[4 * g], q1 = qs[4 * g + 1], q2 = qs[4 * g + 2], q3 = qs[4 * g + 3];
        acc.x += q0 * k0.x + q1 * k1.x + q2 * k2.x + q3 * k3.x;
        acc.y += q0 * k0.y + q1 * k1.y + q2 * k2.y + q3 * k3.y;
        acc.z += q0 * k0.z + q1 * k1.z + q2 * k2.z + q3 * k3.z;
        acc.w += q0 * k0.w + q1 * k1.w + q2 * k2.w + q3 * k3.w;
    }
    *(float4*)(part + (size_t)blockIdx.y * TPREV + t) = acc;
}

// ---------------------------------------------------------------------------
// K3: reduce 128 chunks + sigmoid. grid 65 blocks.
// Blocks 0..63: block owns 128 t (32 float4). 8 slices x 16 chunks each,
// float4 loads, LDS combine, sigmoid, store.
// Block 64: tail a[8192] = sigmoid(dot(q,k)/64).
__global__ __launch_bounds__(256) void reduce_sigmoid_kernel(
    float* __restrict__ ws) {
    if (blockIdx.x < 64) {
        const float4* p = (const float4*)(ws + WS_PART);
        int f4    = threadIdx.x & 31;     // float4 index within block's t-range
        int slice = threadIdx.x >> 5;     // 0..7, each covers 16 chunks
        size_t idx = (size_t)(slice * 16) * (TPREV / 4) + (size_t)blockIdx.x * 32 + f4;

        float4 s = {0.f, 0.f, 0.f, 0.f};
#pragma unroll 4
        for (int c = 0; c < 16; ++c) {
            float4 v = p[idx + (size_t)c * (TPREV / 4)];
            s.x += v.x; s.y += v.y; s.z += v.z; s.w += v.w;
        }
        __shared__ float4 red[256];
        red[threadIdx.x] = s;
        __syncthreads();
        if (threadIdx.x < 32) {
            float4 tot = red[threadIdx.x];
#pragma unroll
            for (int sl = 1; sl < 8; ++sl) {
                float4 v = red[sl * 32 + threadIdx.x];
                tot.x += v.x; tot.y += v.y; tot.z += v.z; tot.w += v.w;
            }
            tot.x = 1.0f / (1.0f + __expf(-tot.x * 0.015625f));
            tot.y = 1.0f / (1.0f + __expf(-tot.y * 0.015625f));
            tot.z = 1.0f / (1.0f + __expf(-tot.z * 0.015625f));
            tot.w = 1.0f / (1.0f + __expf(-tot.w * 0.015625f));
            ((float4*)(ws + WS_A))[(size_t)blockIdx.x * 32 + threadIdx.x] = tot;
        }
    } else {
        // tail: dot(q, k) over 4096 elems, 16 per thread
        const float* q = ws + WS_Q;
        const float* k = ws + WS_K;
        float s = 0.0f;
        int base = threadIdx.x * 16;
#pragma unroll 16
        for (int i = 0; i < 16; ++i) s += q[base + i] * k[base + i];
        __shared__ float red[256];
        red[threadIdx.x] = s;
        __syncthreads();
        for (int off = 128; off > 0; off >>= 1) {
            if (threadIdx.x < off) red[threadIdx.x] += red[threadIdx.x + off];
            __syncthreads();
        }
        if (threadIdx.x == 0) {
            float v = red[0] * 0.015625f;
            ws[WS_A + TPREV] = 1.0f / (1.0f + __expf(-v));
        }
    }
}

// ---------------------------------------------------------------------------
// K4: z[d] = dot(V_cache[d,:], a) + v[d]*a[8192]. Block-per-row: 4096 blocks.
// 2 groups of (4 V loads + 4 a loads) issued independently.
__global__ __launch_bounds__(256) void out_kernel(
    const float* __restrict__ Vc, const float* __restrict__ ws,
    float* __restrict__ out) {
    int d = blockIdx.x;
    const float4* row = (const float4*)(Vc + (size_t)d * TPREV);
    const float4* av  = (const float4*)(ws + WS_A);
    int tid = threadIdx.x;

    float s = 0.0f;
#pragma unroll
    for (int g = 0; g < 2; ++g) {
        int o = g * 1024;
        float4 v0 = row[o + tid];
        float4 v1 = row[o + tid + 256];
        float4 v2 = row[o + tid + 512];
        float4 v3 = row[o + tid + 768];
        float4 a0 = av[o + tid];
        float4 a1 = av[o + tid + 256];
        float4 a2 = av[o + tid + 512];
        float4 a3 = av[o + tid + 768];
        s += dot4(v0, a0) + dot4(v1, a1) + dot4(v2, a2) + dot4(v3, a3);
    }

#pragma unroll
    for (int off = 32; off > 0; off >>= 1) s += __shfl_down(s, off, 64);

    __shared__ float red[4];
    if ((tid & 63) == 0) red[tid >> 6] = s;
    __syncthreads();
    if (tid == 0)
        out[d] = red[0] + red[1] + red[2] + red[3]
               + ws[WS_V + d] * ws[WS_A + TPREV];
}

// ---------------------------------------------------------------------------
extern "C" void kernel_launch(void* const* d_in, const int* in_sizes, int n_in,
                              void* d_out, int out_size, void* d_ws, size_t ws_size,
                              hipStream_t stream) {
    const float* x  = (const float*)d_in[0];
    const float* Wq = (const float*)d_in[1];
    const float* Wk = (const float*)d_in[2];
    const float* Wv = (const float*)d_in[3];
    const float* Kc = (const float*)d_in[4];
    const float* Vc = (const float*)d_in[5];
    float* out = (float*)d_out;
    float* ws  = (float*)d_ws;

    qkv_kernel<<<12288, 256, 0, stream>>>(x, Wq, Wk, Wv, ws);
    score_kernel<<<dim3(8, 128), 256, 0, stream>>>(Kc, ws);
    reduce_sigmoid_kernel<<<65, 256, 0, stream>>>(ws);
    out_kernel<<<4096, 256, 0, stream>>>(Vc, ws, out);
}